// Round 2
// baseline (574.274 us; speedup 1.0000x reference)
//
#include <hip/hip_runtime.h>

// Fused LSTM(78->8, T=64) + FC(8->16) + ReLU + FC(16->11) + softmax.
// B=16384 rows. One block = 32 rows, 256 threads, 4 timesteps staged per iter.
// x is read exactly once (327 MB) -> memory floor ~52us; VALU budget ~60us.
// R1 change vs R0: staging addresses computed incrementally (no per-element
// div/mod by 78) -- saves ~5-6K VALU instrs/thread (~15% of VALU budget).

#define B_SZ 16384
#define T_SZ 64
#define IN_SZ 78
#define H_SZ 8
#define G_SZ 32           // 4*H gates
#define NCLS 11
#define NB 32             // batch rows per block
#define TT 4              // timesteps per outer iteration
#define NTHREADS 256
#define ACT_STRIDE 33     // pad to kill LDS bank conflicts
#define ROW_STRIDE (T_SZ * IN_SZ)   // 4992 floats per batch row in x

__global__ __launch_bounds__(NTHREADS)
void lstm_fused(const float* __restrict__ x,
                const float* __restrict__ W_ih,
                const float* __restrict__ W_hh,
                const float* __restrict__ b_ih,
                const float* __restrict__ b_hh,
                const float* __restrict__ W1,
                const float* __restrict__ b1,
                const float* __restrict__ W2,
                const float* __restrict__ b2,
                float* __restrict__ out)
{
    __shared__ float x_lds[TT * NB * IN_SZ];   // [tt][row][k], 9984 floats
    __shared__ float WihT[IN_SZ * G_SZ];       // [k][g]  (transposed: b64 reads, g0 even)
    __shared__ float WhhT[H_SZ * G_SZ];        // [j][g]
    __shared__ float actT[G_SZ * ACT_STRIDE];  // [g][r]  activated gates (reused as z1T)
    __shared__ float hT[H_SZ * NB];            // [j][r]
    __shared__ float bias_l[G_SZ];
    __shared__ float W1_l[16 * 8];
    __shared__ float b1_l[16];
    __shared__ float W2_l[NCLS * 16];
    __shared__ float b2_l[NCLS];

    const int tid = threadIdx.x;
    const int rowbase = blockIdx.x * NB;

    // ---- one-time weight staging (conflicts here are once-per-kernel) ----
    for (int i = tid; i < IN_SZ * G_SZ; i += NTHREADS) {
        int g = i / IN_SZ, k = i - g * IN_SZ;
        WihT[k * G_SZ + g] = W_ih[i];
    }
    for (int i = tid; i < G_SZ * H_SZ; i += NTHREADS) {
        int g = i / H_SZ, j = i - g * H_SZ;
        WhhT[j * G_SZ + g] = W_hh[i];
    }
    if (tid < G_SZ)      bias_l[tid] = b_ih[tid] + b_hh[tid];
    if (tid < 128)       W1_l[tid] = W1[tid];
    if (tid < 16)        b1_l[tid] = b1[tid];
    if (tid < NCLS * 16) W2_l[tid] = W2[tid];
    if (tid < NCLS)      b2_l[tid] = b2[tid];
    hT[tid] = 0.0f;                 // 8*32 = 256 entries exactly
    __syncthreads();

    // compute-tile role: 2 rows x 2 gates x TT timesteps per thread
    const int rg = tid & 15;        // row group  -> rows 2rg, 2rg+1
    const int gg = tid >> 4;        // gate group -> gates 2gg, 2gg+1
    const int r0 = rg * 2;
    const int g0 = gg * 2;
    const float bias0 = bias_l[g0];
    const float bias1 = bias_l[g0 + 1];
    const bool isTanh = (g0 >= 16) && (g0 < 24);   // g-gate block

    // owner role: one (j, row) cell per thread; c lives in a register
    const int oj = tid >> 5;        // 0..7
    const int orr = tid & 31;       // 0..31
    float c_reg = 0.0f;

    // staging-address seed for element i0 = tid (tt0 == 0 since tid < 2496):
    //   row0 = tid / 78, k0s = tid % 78, goff0 = row0*ROW_STRIDE + k0s
    // per +256 elements: k += 22, row += 3; wraps handled incrementally.
    const int row_seed = tid / IN_SZ;
    const int k_seed = tid - row_seed * IN_SZ;
    const int goff_seed = row_seed * ROW_STRIDE + k_seed;
    const float* xblk = x + (size_t)rowbase * ROW_STRIDE;

    for (int it = 0; it < T_SZ / TT; ++it) {
        const int t0 = it * TT;
        const float* xit = xblk + t0 * IN_SZ;   // uniform per iteration

        // ---- stage TT timesteps of x for this block's 32 rows ----
        // 9984 floats = 39 per thread; LDS writes linear in i = tid + j*256.
        {
            int k = k_seed;
            int row = row_seed;
            int goff = goff_seed;
            #pragma unroll
            for (int j = 0; j < 39; ++j) {
                x_lds[tid + j * NTHREADS] = xit[goff];
                // advance by 256 elements in [tt][row][k] space
                k += 22; row += 3; goff += 3 * ROW_STRIDE + 22;        // 14998
                if (k >= IN_SZ) { k -= IN_SZ; row += 1; goff += ROW_STRIDE - IN_SZ; } // +4914
                if (row >= NB)  { row -= NB; goff += IN_SZ - NB * ROW_STRIDE; }       // -159666
            }
        }
        __syncthreads();

        // ---- input projection: acc[tt][rr][g2] = bias + sum_k x*W ----
        float acc[TT][2][2];
        #pragma unroll
        for (int tt = 0; tt < TT; ++tt) {
            acc[tt][0][0] = bias0; acc[tt][0][1] = bias1;
            acc[tt][1][0] = bias0; acc[tt][1][1] = bias1;
        }

        #pragma unroll 3
        for (int k0 = 0; k0 < IN_SZ; k0 += 2) {
            float2 w0 = *(const float2*)&WihT[(k0    ) * G_SZ + g0]; // W[g0][k0], W[g0+1][k0]
            float2 w1 = *(const float2*)&WihT[(k0 + 1) * G_SZ + g0];
            #pragma unroll
            for (int tt = 0; tt < TT; ++tt) {
                #pragma unroll
                for (int rr = 0; rr < 2; ++rr) {
                    float2 xv = *(const float2*)&x_lds[(tt * NB + r0 + rr) * IN_SZ + k0];
                    acc[tt][rr][0] += xv.x * w0.x + xv.y * w1.x;
                    acc[tt][rr][1] += xv.x * w0.y + xv.y * w1.y;
                }
            }
        }

        // ---- sequential LSTM updates for the TT staged timesteps ----
        #pragma unroll
        for (int tt = 0; tt < TT; ++tt) {
            // recurrent contribution from h(t-1)
            float rec[2][2] = {{0.f, 0.f}, {0.f, 0.f}};
            #pragma unroll
            for (int j = 0; j < H_SZ; ++j) {
                float2 hv = *(const float2*)&hT[j * NB + r0];     // h[r0][j], h[r0+1][j]
                float2 wv = *(const float2*)&WhhT[j * G_SZ + g0]; // Whh[g0][j], Whh[g0+1][j]
                rec[0][0] += hv.x * wv.x;  rec[0][1] += hv.x * wv.y;
                rec[1][0] += hv.y * wv.x;  rec[1][1] += hv.y * wv.y;
            }
            // activation (sigmoid for i,f,o; tanh for g) -> actT
            #pragma unroll
            for (int rr = 0; rr < 2; ++rr) {
                #pragma unroll
                for (int g2 = 0; g2 < 2; ++g2) {
                    float v = acc[tt][rr][g2] + rec[rr][g2];
                    float arg = isTanh ? 2.0f * v : v;
                    float s = 1.0f / (1.0f + __expf(-arg));
                    float a = isTanh ? (2.0f * s - 1.0f) : s;
                    actT[(g0 + g2) * ACT_STRIDE + (r0 + rr)] = a;
                }
            }
            __syncthreads();
            // owner: c,h update
            {
                float iv = actT[(oj     ) * ACT_STRIDE + orr];
                float fv = actT[(oj +  8) * ACT_STRIDE + orr];
                float gv = actT[(oj + 16) * ACT_STRIDE + orr];
                float ov = actT[(oj + 24) * ACT_STRIDE + orr];
                c_reg = fv * c_reg + iv * gv;
                float s = 1.0f / (1.0f + __expf(-2.0f * c_reg));
                float th = 2.0f * s - 1.0f;
                hT[oj * NB + orr] = ov * th;
            }
            __syncthreads();
        }
    }

    // ---- classifier epilogue: relu(h) -> 16 -> relu -> 11 -> softmax ----
    float* z1T = actT;   // reuse (gates dead now), stride ACT_STRIDE
    {
        const int r = tid & 31;
        const int uu = tid >> 5;        // 0..7 -> units 2uu, 2uu+1
        float hr[H_SZ];
        #pragma unroll
        for (int j = 0; j < H_SZ; ++j) hr[j] = fmaxf(hT[j * NB + r], 0.0f);
        #pragma unroll
        for (int u2 = 0; u2 < 2; ++u2) {
            int u = uu * 2 + u2;
            float z = b1_l[u];
            #pragma unroll
            for (int j = 0; j < H_SZ; ++j) z += hr[j] * W1_l[u * 8 + j];
            z1T[u * ACT_STRIDE + r] = fmaxf(z, 0.0f);
        }
    }
    __syncthreads();
    if (tid < NB) {
        const int r = tid;
        float z1v[16];
        #pragma unroll
        for (int u = 0; u < 16; ++u) z1v[u] = z1T[u * ACT_STRIDE + r];
        float z2[NCLS];
        float m = -1e30f;
        #pragma unroll
        for (int c = 0; c < NCLS; ++c) {
            float v = b2_l[c];
            #pragma unroll
            for (int u = 0; u < 16; ++u) v += z1v[u] * W2_l[c * 16 + u];
            z2[c] = v;
            m = fmaxf(m, v);
        }
        float s = 0.0f;
        #pragma unroll
        for (int c = 0; c < NCLS; ++c) { z2[c] = __expf(z2[c] - m); s += z2[c]; }
        float inv = 1.0f / s;
        float* op = out + (size_t)(rowbase + r) * NCLS;
        #pragma unroll
        for (int c = 0; c < NCLS; ++c) op[c] = z2[c] * inv;
    }
}

extern "C" void kernel_launch(void* const* d_in, const int* in_sizes, int n_in,
                              void* d_out, int out_size, void* d_ws, size_t ws_size,
                              hipStream_t stream) {
    const float* x    = (const float*)d_in[0];
    const float* W_ih = (const float*)d_in[1];
    const float* W_hh = (const float*)d_in[2];
    const float* b_ih = (const float*)d_in[3];
    const float* b_hh = (const float*)d_in[4];
    const float* W1   = (const float*)d_in[5];
    const float* b1   = (const float*)d_in[6];
    const float* W2   = (const float*)d_in[7];
    const float* b2   = (const float*)d_in[8];
    float* outp = (float*)d_out;

    lstm_fused<<<dim3(B_SZ / NB), dim3(NTHREADS), 0, stream>>>(
        x, W_ih, W_hh, b_ih, b_hh, W1, b1, W2, b2, outp);
}

// Round 5
// 505.541 us; speedup vs baseline: 1.1360x; 1.1360x over previous
//
#include <hip/hip_runtime.h>

// Fused LSTM(78->8, T=64) + FC(8->16) + ReLU + FC(16->11) + softmax. B=16384.
// R3/R4/R5 restructure: 16 rows/block (1024 blocks, 4/CU), shfl-based
// wave-local recurrence (no barriers per timestep), conflict-free LDS layouts,
// float2 packed-FMA projection, loads-before-recurrence software pipeline.
// (R5 = resubmission; GPU unavailable two rounds running, kernel never ran.)

typedef float v2f __attribute__((ext_vector_type(2)));

#define B_SZ 16384
#define T_SZ 64
#define IN_SZ 78
#define H_SZ 8
#define NCLS 11
#define NB 16              // rows per block
#define TT 4               // timesteps per tile
#define NTHREADS 256
#define NITER (T_SZ / TT)  // 16
#define K2 (IN_SZ / 2)     // 39 float2 per row
#define XTILE (TT * NB * K2)       // 2496 float2 per tile
#define ROWSTR (T_SZ * IN_SZ)      // 4992 floats per batch row

__device__ __forceinline__ float sigm(float x) { return 1.0f / (1.0f + __expf(-x)); }

__device__ __forceinline__ v2f shfl2(v2f v, int srcLane) {
    v2f r;
    r.x = __shfl(v.x, srcLane, 64);
    r.y = __shfl(v.y, srcLane, 64);
    return r;
}

__global__ __launch_bounds__(NTHREADS, 4)
void lstm_fused(const float* __restrict__ x,
                const float* __restrict__ W_ih,
                const float* __restrict__ W_hh,
                const float* __restrict__ b_ih,
                const float* __restrict__ b_hh,
                const float* __restrict__ W1,
                const float* __restrict__ b1,
                const float* __restrict__ W2,
                const float* __restrict__ b2,
                float* __restrict__ out)
{
    __shared__ v2f   x2[XTILE];          // [tt][row][k2]   19968 B
    __shared__ float WihT[IN_SZ * 32];   // [k][g]           9984 B
    __shared__ float z1s[NB][17];        //                  1088 B

    const int tid = threadIdx.x;
    const int gg  = tid & 15;           // gate pair: gates {2gg, 2gg+1}
    const int r   = tid >> 4;           // row 0..15 (4 per wave)
    const int lane = tid & 63;
    const int typeIdx = gg >> 2;        // 0:i 1:f 2:g 3:o
    const bool isT = (typeIdx == 2);
    const int pr = gg & 3;              // j-pair: j in {2pr, 2pr+1}
    const int laneBase = (lane & 0x30) | pr;   // same r, type 0, same pair
    const int laneQ    = lane & ~3;            // same r+type, pair 0

    const size_t rowbase = (size_t)blockIdx.x * NB;
    const float* xb = x + rowbase * ROWSTR;

    // ---- per-thread constant registers ----
    const int G0 = 2 * gg, G1 = 2 * gg + 1;
    v2f bias; bias.x = b_ih[G0] + b_hh[G0]; bias.y = b_ih[G1] + b_hh[G1];
    v2f Whh_r[H_SZ];   // Whh_r[j] = {W_hh[G0][j], W_hh[G1][j]}
    #pragma unroll
    for (int j = 0; j < H_SZ; ++j) {
        Whh_r[j].x = W_hh[G0 * H_SZ + j];
        Whh_r[j].y = W_hh[G1 * H_SZ + j];
    }

    // ---- staging address table: 10 rounds of float2, p = tid + 256*j ----
    int goff[10];
    {
        int trow = tid / K2;            // [tt][row] combined: tt = trow>>4, row = trow&15
        int k2   = tid - trow * K2;
        #pragma unroll
        for (int j = 0; j < 10; ++j) {
            goff[j] = (trow & (NB - 1)) * ROWSTR + (trow >> 4) * IN_SZ + 2 * k2;
            trow += 6; k2 += 22;
            if (k2 >= K2) { k2 -= K2; trow += 1; }
        }
    }

    // ---- prologue: stage W_ih (transposed) + x tile 0 ----
    v2f xv[10];
    #pragma unroll
    for (int j = 0; j < 9; ++j) xv[j] = *(const v2f*)&xb[goff[j]];
    if (tid < 192)              xv[9] = *(const v2f*)&xb[goff[9]];

    float wtmp[10];
    #pragma unroll
    for (int j = 0; j < 10; ++j) {
        int p = tid + j * NTHREADS;
        if (j < 9 || tid < 192) wtmp[j] = W_ih[p];
    }
    #pragma unroll
    for (int j = 0; j < 10; ++j) {
        int p = tid + j * NTHREADS;
        if (j < 9 || tid < 192) {
            int g = p / IN_SZ, k = p - g * IN_SZ;
            WihT[k * 32 + g] = wtmp[j];
        }
    }
    #pragma unroll
    for (int j = 0; j < 9; ++j) x2[tid + j * NTHREADS] = xv[j];
    if (tid < 192)              x2[tid + 9 * NTHREADS] = xv[9];
    __syncthreads();

    // ---- LSTM state (wave-local, canonical) ----
    v2f c2;   c2.x = 0.0f; c2.y = 0.0f;       // c for j-pair pr
    v2f hq[4];                                 // all 8 h values, canonical
    #pragma unroll
    for (int q = 0; q < 4; ++q) { hq[q].x = 0.0f; hq[q].y = 0.0f; }

    // ---- projection of tile 0 ----
    v2f acc[TT];
    #pragma unroll
    for (int tt = 0; tt < TT; ++tt) acc[tt] = bias;
    #pragma unroll 3
    for (int k0 = 0; k0 < IN_SZ; k0 += 2) {
        v2f w0 = *(const v2f*)&WihT[(k0    ) * 32 + G0];
        v2f w1 = *(const v2f*)&WihT[(k0 + 1) * 32 + G0];
        #pragma unroll
        for (int tt = 0; tt < TT; ++tt) {
            v2f xk = x2[(tt * NB + r) * K2 + (k0 >> 1)];
            v2f sx; sx.x = xk.x; sx.y = xk.x;
            v2f sy; sy.x = xk.y; sy.y = xk.y;
            acc[tt] += sx * w0;
            acc[tt] += sy * w1;
        }
    }

    // ---- main pipeline: iters 1..15 ----
    for (int it = 1; it < NITER; ++it) {
        const float* xit = xb + it * (TT * IN_SZ);
        // (1) issue next tile's global loads
        #pragma unroll
        for (int j = 0; j < 9; ++j) xv[j] = *(const v2f*)&xit[goff[j]];
        if (tid < 192)              xv[9] = *(const v2f*)&xit[goff[9]];

        // (2) recurrence for previous tile (registers + shfl only)
        #pragma unroll
        for (int tt = 0; tt < TT; ++tt) {
            v2f v = acc[tt];
            #pragma unroll
            for (int q = 0; q < 4; ++q) {
                v2f hx; hx.x = hq[q].x; hx.y = hq[q].x;
                v2f hy; hy.x = hq[q].y; hy.y = hq[q].y;
                v += hx * Whh_r[2 * q];
                v += hy * Whh_r[2 * q + 1];
            }
            v2f a;
            {
                float ax = isT ? 2.0f * v.x : v.x;
                float ay = isT ? 2.0f * v.y : v.y;
                float sxv = sigm(ax), syv = sigm(ay);
                a.x = isT ? 2.0f * sxv - 1.0f : sxv;
                a.y = isT ? 2.0f * syv - 1.0f : syv;
            }
            v2f i2 = shfl2(a, laneBase);
            v2f f2 = shfl2(a, laneBase + 4);
            v2f g2 = shfl2(a, laneBase + 8);
            v2f o2 = shfl2(a, laneBase + 12);
            c2 = f2 * c2 + i2 * g2;
            v2f th;
            th.x = 2.0f * sigm(2.0f * c2.x) - 1.0f;
            th.y = 2.0f * sigm(2.0f * c2.y) - 1.0f;
            v2f h2 = o2 * th;
            hq[0] = shfl2(h2, laneQ);
            hq[1] = shfl2(h2, laneQ | 1);
            hq[2] = shfl2(h2, laneQ | 2);
            hq[3] = shfl2(h2, laneQ | 3);
        }

        // (3) publish next tile to LDS
        __syncthreads();   // all waves done reading previous tile
        #pragma unroll
        for (int j = 0; j < 9; ++j) x2[tid + j * NTHREADS] = xv[j];
        if (tid < 192)              x2[tid + 9 * NTHREADS] = xv[9];
        __syncthreads();

        // (4) projection of this tile
        #pragma unroll
        for (int tt = 0; tt < TT; ++tt) acc[tt] = bias;
        #pragma unroll 3
        for (int k0 = 0; k0 < IN_SZ; k0 += 2) {
            v2f w0 = *(const v2f*)&WihT[(k0    ) * 32 + G0];
            v2f w1 = *(const v2f*)&WihT[(k0 + 1) * 32 + G0];
            #pragma unroll
            for (int tt = 0; tt < TT; ++tt) {
                v2f xk = x2[(tt * NB + r) * K2 + (k0 >> 1)];
                v2f sx; sx.x = xk.x; sx.y = xk.x;
                v2f sy; sy.x = xk.y; sy.y = xk.y;
                acc[tt] += sx * w0;
                acc[tt] += sy * w1;
            }
        }
    }

    // ---- epilogue: recurrence for last tile ----
    #pragma unroll
    for (int tt = 0; tt < TT; ++tt) {
        v2f v = acc[tt];
        #pragma unroll
        for (int q = 0; q < 4; ++q) {
            v2f hx; hx.x = hq[q].x; hx.y = hq[q].x;
            v2f hy; hy.x = hq[q].y; hy.y = hq[q].y;
            v += hx * Whh_r[2 * q];
            v += hy * Whh_r[2 * q + 1];
        }
        v2f a;
        {
            float ax = isT ? 2.0f * v.x : v.x;
            float ay = isT ? 2.0f * v.y : v.y;
            float sxv = sigm(ax), syv = sigm(ay);
            a.x = isT ? 2.0f * sxv - 1.0f : sxv;
            a.y = isT ? 2.0f * syv - 1.0f : syv;
        }
        v2f i2 = shfl2(a, laneBase);
        v2f f2 = shfl2(a, laneBase + 4);
        v2f g2 = shfl2(a, laneBase + 8);
        v2f o2 = shfl2(a, laneBase + 12);
        c2 = f2 * c2 + i2 * g2;
        v2f th;
        th.x = 2.0f * sigm(2.0f * c2.x) - 1.0f;
        th.y = 2.0f * sigm(2.0f * c2.y) - 1.0f;
        v2f h2 = o2 * th;
        hq[0] = shfl2(h2, laneQ);
        hq[1] = shfl2(h2, laneQ | 1);
        hq[2] = shfl2(h2, laneQ | 2);
        hq[3] = shfl2(h2, laneQ | 3);
    }

    // ---- classifier: lane gg computes hidden unit u=gg for its row ----
    {
        float z1 = b1[gg];
        #pragma unroll
        for (int q = 0; q < 4; ++q) {
            z1 += fmaxf(hq[q].x, 0.0f) * W1[gg * H_SZ + 2 * q];
            z1 += fmaxf(hq[q].y, 0.0f) * W1[gg * H_SZ + 2 * q + 1];
        }
        z1s[r][gg] = fmaxf(z1, 0.0f);
    }
    __syncthreads();
    if (tid < NB) {
        const int row = tid;
        float z1v[16];
        #pragma unroll
        for (int u = 0; u < 16; ++u) z1v[u] = z1s[row][u];
        float z2[NCLS];
        float m = -1e30f;
        #pragma unroll
        for (int c = 0; c < NCLS; ++c) {
            float v = b2[c];
            #pragma unroll
            for (int u = 0; u < 16; ++u) v += z1v[u] * W2[c * 16 + u];
            z2[c] = v;
            m = fmaxf(m, v);
        }
        float s = 0.0f;
        #pragma unroll
        for (int c = 0; c < NCLS; ++c) { z2[c] = __expf(z2[c] - m); s += z2[c]; }
        float inv = 1.0f / s;
        float* op = out + (rowbase + row) * NCLS;
        #pragma unroll
        for (int c = 0; c < NCLS; ++c) op[c] = z2[c] * inv;
    }
}

extern "C" void kernel_launch(void* const* d_in, const int* in_sizes, int n_in,
                              void* d_out, int out_size, void* d_ws, size_t ws_size,
                              hipStream_t stream) {
    const float* x    = (const float*)d_in[0];
    const float* W_ih = (const float*)d_in[1];
    const float* W_hh = (const float*)d_in[2];
    const float* b_ih = (const float*)d_in[3];
    const float* b_hh = (const float*)d_in[4];
    const float* W1   = (const float*)d_in[5];
    const float* b1   = (const float*)d_in[6];
    const float* W2   = (const float*)d_in[7];
    const float* b2   = (const float*)d_in[8];
    float* outp = (float*)d_out;

    lstm_fused<<<dim3(B_SZ / NB), dim3(NTHREADS), 0, stream>>>(
        x, W_ih, W_hh, b_ih, b_hh, W1, b1, W2, b2, outp);
}